// Round 1
// baseline (373.157 us; speedup 1.0000x reference)
//
#include <hip/hip_runtime.h>
#include <math.h>

// Problem constants (from reference): D=2048, E=8, T=32768, top_k=2
constexpr int D_DIM = 2048;
constexpr int NEXP  = 8;
constexpr int NTOK  = 32768;
constexpr int TT    = 8;    // tokens per wave
constexpr int KC    = 128;  // k-chunk; each of 64 lanes owns 2 consecutive k
constexpr int WPB   = 4;    // waves per block (block = 256 threads)

__device__ __forceinline__ float softplus_f(float x) {
    // stable softplus; matches log1p(exp(x)) with overflow guard
    return (x > 20.0f) ? x : log1pf(expf(x));
}

__global__ __launch_bounds__(256, 2)
void noisy_topk_router(const float* __restrict__ h,
                       const float* __restrict__ Ww,
                       const float* __restrict__ bw,
                       const float* __restrict__ Wn,
                       const float* __restrict__ bn,
                       const float* __restrict__ eps,
                       float* __restrict__ out_sparse,
                       float* __restrict__ out_ix,
                       float* __restrict__ out_full)
{
    const int lane = threadIdx.x & 63;
    const int wave = threadIdx.x >> 6;
    const int t0   = (blockIdx.x * WPB + wave) * TT;

    // p[v], v = t*16 + e ; e in [0,8) -> W_w expert e, e in [8,16) -> W_n expert e-8
    float p[TT * 16];
#pragma unroll
    for (int i = 0; i < TT * 16; ++i) p[i] = 0.0f;

    const float* hbase = h + (size_t)t0 * D_DIM;

#pragma unroll 2
    for (int k0 = 0; k0 < D_DIM; k0 += KC) {
        const int kk = k0 + lane * 2;  // this lane's 2 k-rows in this chunk
        // W rows kk and kk+1 from both matrices (row-major [D][8])
        const float4* wwp = (const float4*)(Ww + (size_t)kk * NEXP);
        const float4* wnp = (const float4*)(Wn + (size_t)kk * NEXP);
        float4 ww0 = wwp[0], ww1 = wwp[1], ww2 = wwp[2], ww3 = wwp[3];
        float4 wn0 = wnp[0], wn1 = wnp[1], wn2 = wnp[2], wn3 = wnp[3];

        float wrow0[16] = {ww0.x, ww0.y, ww0.z, ww0.w, ww1.x, ww1.y, ww1.z, ww1.w,
                           wn0.x, wn0.y, wn0.z, wn0.w, wn1.x, wn1.y, wn1.z, wn1.w};
        float wrow1[16] = {ww2.x, ww2.y, ww2.z, ww2.w, ww3.x, ww3.y, ww3.z, ww3.w,
                           wn2.x, wn2.y, wn2.z, wn2.w, wn3.x, wn3.y, wn3.z, wn3.w};

        float2 hv[TT];
#pragma unroll
        for (int t = 0; t < TT; ++t)
            hv[t] = *(const float2*)(hbase + (size_t)t * D_DIM + kk);

#pragma unroll
        for (int t = 0; t < TT; ++t) {
            const float x0 = hv[t].x, x1 = hv[t].y;
#pragma unroll
            for (int j = 0; j < 16; ++j) {
                p[t * 16 + j] = fmaf(x0, wrow0[j], p[t * 16 + j]);
                p[t * 16 + j] = fmaf(x1, wrow1[j], p[t * 16 + j]);
            }
        }
    }

    // Compacting reduce-scatter across 64 lanes.
    // Invariant before step s: compact index j holds value v = (j<<s) | (lane & (2^s-1)).
    // After 6 steps lane L holds p[0] -> v=L, p[1] -> v=L+64.
#pragma unroll
    for (int s = 0; s < 6; ++s) {
        const int m = 1 << s;
        const bool hi = (lane & m) != 0;
        const int n = (TT * 16) >> (s + 1);
#pragma unroll
        for (int j = 0; j < n; ++j) {
            float a  = p[2 * j];
            float b  = p[2 * j + 1];
            float ta = __shfl_xor(a, m, 64);
            float tb = __shfl_xor(b, m, 64);
            p[j] = hi ? (b + tb) : (a + ta);
        }
    }

    // Epilogue: lane L holds (token t0 + (L>>4) + 4q, output e=L&15) for q=0,1.
    const int  e16       = lane & 15;
    const int  eg        = lane & 7;
    const bool noiseLane = (e16 & 8) != 0;
    const int  trow      = lane >> 4;
    const float bias     = noiseLane ? bn[eg] : bw[eg];

#pragma unroll
    for (int q = 0; q < 2; ++q) {
        const int tok = t0 + trow + 4 * q;
        const float val = p[q] + bias;              // logit (e<8) or noise-logit (e>=8)
        const float sp  = softplus_f(val);          // used from noise lanes
        const float spN = __shfl_xor(sp, 8, 64);    // logit lane <- partner's softplus
        const float ev  = eps[(size_t)tok * NEXP + eg];
        const float noisy = val + ev * spN;         // meaningful on logit lanes (e<8)

        // argmax over the 8 logit lanes (ties -> lower index, like lax.top_k)
        float v0 = noisy; int i0 = eg;
#pragma unroll
        for (int m = 1; m <= 4; m <<= 1) {
            float ov = __shfl_xor(v0, m, 64);
            int   oi = __shfl_xor(i0, m, 64);
            bool take = (ov > v0) || (ov == v0 && oi < i0);
            v0 = take ? ov : v0;
            i0 = take ? oi : i0;
        }
        // second argmax (exclude i0)
        float v1 = (eg == i0) ? -INFINITY : noisy; int i1 = eg;
#pragma unroll
        for (int m = 1; m <= 4; m <<= 1) {
            float ov = __shfl_xor(v1, m, 64);
            int   oi = __shfl_xor(i1, m, 64);
            bool take = (ov > v1) || (ov == v1 && oi < i1);
            v1 = take ? ov : v1;
            i1 = take ? oi : i1;
        }
        // full softmax over 8 experts
        const float ex = expf(noisy - v0);
        float ssum = ex;
#pragma unroll
        for (int m = 1; m <= 4; m <<= 1) ssum += __shfl_xor(ssum, m, 64);
        const float fullv = ex / ssum;
        // sparse softmax over the top-2 (others are exactly 0)
        const float dd  = expf(v1 - v0);
        const float den = 1.0f + dd;
        const float sparsev = (eg == i0) ? (1.0f / den)
                            : (eg == i1) ? (dd / den) : 0.0f;

        if (!noiseLane) {
            out_sparse[(size_t)tok * NEXP + eg] = sparsev;
            out_full  [(size_t)tok * NEXP + eg] = fullv;
            if (eg == 0) {
                out_ix[(size_t)tok * 2]     = (float)i0;
                out_ix[(size_t)tok * 2 + 1] = (float)i1;
            }
        }
    }
}

extern "C" void kernel_launch(void* const* d_in, const int* in_sizes, int n_in,
                              void* d_out, int out_size, void* d_ws, size_t ws_size,
                              hipStream_t stream) {
    const float* h   = (const float*)d_in[0];
    const float* Ww  = (const float*)d_in[1];
    const float* bw  = (const float*)d_in[2];
    const float* Wn  = (const float*)d_in[3];
    const float* bn  = (const float*)d_in[4];
    const float* eps = (const float*)d_in[5];
    // d_in[6] = top_k (always 2 for this problem)

    float* out_sparse = (float*)d_out;                         // [T, 8]
    float* out_ix     = out_sparse + (size_t)NTOK * NEXP;      // [T, 2] (as float)
    float* out_full   = out_ix + (size_t)NTOK * 2;             // [T, 8]

    const int grid = NTOK / (TT * WPB);  // 1024 blocks x 256 threads
    noisy_topk_router<<<grid, 256, 0, stream>>>(h, Ww, bw, Wn, bn, eps,
                                                out_sparse, out_ix, out_full);
}